// Round 1
// baseline (767.199 us; speedup 1.0000x reference)
//
#include <hip/hip_runtime.h>
#include <hip/hip_cooperative_groups.h>
#include <math.h>

namespace cg = cooperative_groups;

// ---------------------------------------------------------------------------
// NeuralODE encoder: h0 = x@Wp.T+bp ; adaptive dopri5 (<=64 steps, global
// err_norm controller) of GRU-cell ODE ; out = hT@Wl.T + bl.
//
// Design (round 0, correctness-first baseline):
//  - 128 blocks x 256 threads, cooperative launch. Block owns 4 batch rows.
//  - Per f-eval: thread t computes gates (r,z,n) at hidden index h=t for its
//    block's 4 rows. y broadcast via v_readlane from per-wave register slices
//    (yq), W streamed from L2 in k-quad layout (prep kernel transposes).
//  - FSAL: k1 reused from k7 on accept. Early exit when t1-t<=1e-6 (exact:
//    reference freezes state after done).
//  - err_norm: deterministic reduction (block LDS tree -> per-block partial ->
//    every block serially sums 128 partials in fixed order). 1 grid.sync/step.
//  - All controller math fp32 to mirror the JAX reference.
//
// ws layout (floats):
//   [0,196608)        Wq  : Wih k-quad transpose  Wq[kq][c][j] = Wih[c][4kq+j]
//   [196608,229376)   Wpt : Wp transpose          Wpt[k][h]    = Wp[h][k]
//   [229376,245760)   Wlt : Wl transpose          Wlt[k][c]    = Wl[c][k]
//   byte 983040..985088 : double partials[2][128] (step-parity double buffer)
// ---------------------------------------------------------------------------

#define NBLK 128
#define F(x) ((float)(x))

static __device__ __forceinline__ float rlane(float v, int l) {
  return __int_as_float(__builtin_amdgcn_readlane(__float_as_int(v), (unsigned)l));
}

__global__ void prep_kernel(const float* __restrict__ Wih,
                            const float* __restrict__ Wp,
                            const float* __restrict__ Wl,
                            float* __restrict__ ws) {
  int i = blockIdx.x * blockDim.x + threadIdx.x;
  if (i < 196608) {
    int j = i & 3, cc = (i >> 2) % 768, kq = (i >> 2) / 768;
    ws[i] = Wih[cc * 257 + kq * 4 + j];
  } else if (i < 229376) {
    int ii = i - 196608; int hh = ii & 255, k = ii >> 8;
    ws[i] = Wp[hh * 128 + k];
  } else if (i < 245760) {
    int ii = i - 229376; int c = ii & 63, k = ii >> 6;
    ws[i] = Wl[c * 256 + k];
  }
}

// One GRU-cell ODE eval for 4 rows at hidden index h (thread-owned).
// yq slices: y{0..3}[q].{x,y,z,w} = y[row 0..3][q*64 + lane]
__device__ __forceinline__ void eval_f(
    const float4* __restrict__ Wq4, int h,
    float4 y0, float4 y1, float4 y2, float4 y3,
    float cbR, float cbZ, float cbN,
    float br_, float bz_, float bn_,
    float kout[4]) {
  float aR[4] = {cbR, cbR, cbR, cbR};
  float aZ[4] = {cbZ, cbZ, cbZ, cbZ};
  float aN[4] = {cbN, cbN, cbN, cbN};
  const float4* pR = Wq4 + h;
  const float4* pZ = Wq4 + 256 + h;
  const float4* pN = Wq4 + 512 + h;
#pragma unroll
  for (int q = 0; q < 4; ++q) {
    float4 yv = (q == 0) ? y0 : (q == 1) ? y1 : (q == 2) ? y2 : y3;
#pragma unroll 4
    for (int kq = 0; kq < 16; ++kq) {
      int kqg = q * 16 + kq;
      float4 wr = pR[(size_t)kqg * 768];
      float4 wz = pZ[(size_t)kqg * 768];
      float4 wn = pN[(size_t)kqg * 768];
#pragma unroll
      for (int j = 0; j < 4; ++j) {
        int ln = kq * 4 + j;  // uniform across the wave
        float a0 = rlane(yv.x, ln);
        float a1 = rlane(yv.y, ln);
        float a2 = rlane(yv.z, ln);
        float a3 = rlane(yv.w, ln);
        float wrj = (j == 0) ? wr.x : (j == 1) ? wr.y : (j == 2) ? wr.z : wr.w;
        float wzj = (j == 0) ? wz.x : (j == 1) ? wz.y : (j == 2) ? wz.z : wz.w;
        float wnj = (j == 0) ? wn.x : (j == 1) ? wn.y : (j == 2) ? wn.z : wn.w;
        aR[0] = fmaf(a0, wrj, aR[0]); aR[1] = fmaf(a1, wrj, aR[1]);
        aR[2] = fmaf(a2, wrj, aR[2]); aR[3] = fmaf(a3, wrj, aR[3]);
        aZ[0] = fmaf(a0, wzj, aZ[0]); aZ[1] = fmaf(a1, wzj, aZ[1]);
        aZ[2] = fmaf(a2, wzj, aZ[2]); aZ[3] = fmaf(a3, wzj, aZ[3]);
        aN[0] = fmaf(a0, wnj, aN[0]); aN[1] = fmaf(a1, wnj, aN[1]);
        aN[2] = fmaf(a2, wnj, aN[2]); aN[3] = fmaf(a3, wnj, aN[3]);
      }
    }
  }
#pragma unroll
  for (int r = 0; r < 4; ++r) {
    float rg = 1.0f / (1.0f + expf(-(aR[r] + br_)));
    float zg = 1.0f / (1.0f + expf(-(aZ[r] + bz_)));
    float ng = tanhf(aN[r] + rg * bn_);
    kout[r] = (1.0f - zg) * ng;
  }
}

// Redistribute ys (thread-owned, h=t) into per-wave register slices, then eval.
#define STAGE(TS, KOUT)                                                        \
  do {                                                                         \
    __syncthreads();                                                           \
    ybuf4[t] = make_float4(ys[0], ys[1], ys[2], ys[3]);                        \
    __syncthreads();                                                           \
    float4 q0 = ybuf4[lane];                                                   \
    float4 q1 = ybuf4[64 + lane];                                              \
    float4 q2 = ybuf4[128 + lane];                                             \
    float4 q3 = ybuf4[192 + lane];                                             \
    float ts_ = (TS);                                                          \
    float cbR = fmaf(ts_, wtR, bihR);                                          \
    float cbZ = fmaf(ts_, wtZ, bihZ);                                          \
    float cbN = fmaf(ts_, wtN, bihN);                                          \
    eval_f(Wq4, h, q0, q1, q2, q3, cbR, cbZ, cbN, br_, bz_, bn_, KOUT);        \
  } while (0)

__global__ void __launch_bounds__(256, 1)
ode_kernel(const float* __restrict__ x,
           const float* __restrict__ tp, int nt,
           const float* __restrict__ bp,
           const float* __restrict__ Wih,
           const float* __restrict__ bih,
           const float* __restrict__ bhh,
           const float* __restrict__ bl,
           const float* __restrict__ ws_f,
           double* __restrict__ partials,
           float* __restrict__ out) {
  __shared__ float4 ybuf4[256];
  __shared__ float xl[512];
  __shared__ double red[256];
  __shared__ double s_bcast;
  cg::grid_group grid = cg::this_grid();

  const int rg = blockIdx.x;
  const int t = threadIdx.x;
  const int lane = t & 63;
  const int w = t >> 6;
  const int h = t;

  const float4* Wq4 = (const float4*)ws_f;
  const float* Wpt = ws_f + 196608;
  const float* Wlt = ws_f + 229376;

  const float t0 = tp[0];
  const float t1v = tp[nt - 1];

  const float br_ = bhh[h], bz_ = bhh[256 + h], bn_ = bhh[512 + h];
  const float bihR = bih[h], bihZ = bih[256 + h], bihN = bih[512 + h];
  const float wtR = Wih[h * 257 + 256];
  const float wtZ = Wih[(256 + h) * 257 + 256];
  const float wtN = Wih[(512 + h) * 257 + 256];

  // ---- h0 = x @ Wp.T + bp (this block's 4 rows) ----
  for (int ii = t; ii < 512; ii += 256)
    xl[ii] = x[(rg * 4 + (ii >> 7)) * 128 + (ii & 127)];
  __syncthreads();
  float y[4];
  {
    float acc[4] = {0.f, 0.f, 0.f, 0.f};
    for (int k = 0; k < 128; ++k) {
      float wv = Wpt[k * 256 + h];
#pragma unroll
      for (int r = 0; r < 4; ++r) acc[r] = fmaf(xl[r * 128 + k], wv, acc[r]);
    }
    const float bpv = bp[h];
#pragma unroll
    for (int r = 0; r < 4; ++r) y[r] = acc[r] + bpv;
  }

  float tcur = t0;
  float dt = (t1v - t0) * 0.01f + 1e-8f;

  float k1[4], k2[4], k3[4], k4[4], k5[4], k6[4], k7[4];
  float ys[4], y5[4];

#pragma unroll
  for (int r = 0; r < 4; ++r) ys[r] = y[r];
  STAGE(tcur, k1);  // initial k1; FSAL afterwards

  for (int step = 0; step < 64; ++step) {
    if (t1v - tcur <= 1e-6f) break;  // exact: ref freezes state once done
    const float dtc = fminf(dt, t1v - tcur);

    // k2 @ t + 0.2 dt
#pragma unroll
    for (int r = 0; r < 4; ++r) ys[r] = fmaf(dtc * 0.2f, k1[r], y[r]);
    STAGE(tcur + dtc * 0.2f, k2);

    // k3 @ t + 0.3 dt
#pragma unroll
    for (int r = 0; r < 4; ++r)
      ys[r] = fmaf(dtc, fmaf(F(9.0 / 40.0), k2[r], F(3.0 / 40.0) * k1[r]), y[r]);
    STAGE(tcur + dtc * 0.3f, k3);

    // k4 @ t + 0.8 dt
#pragma unroll
    for (int r = 0; r < 4; ++r) {
      float in_ = F(44.0 / 45.0) * k1[r];
      in_ = fmaf(F(-56.0 / 15.0), k2[r], in_);
      in_ = fmaf(F(32.0 / 9.0), k3[r], in_);
      ys[r] = fmaf(dtc, in_, y[r]);
    }
    STAGE(tcur + dtc * 0.8f, k4);

    // k5 @ t + (8/9) dt
#pragma unroll
    for (int r = 0; r < 4; ++r) {
      float in_ = F(19372.0 / 6561.0) * k1[r];
      in_ = fmaf(F(-25360.0 / 2187.0), k2[r], in_);
      in_ = fmaf(F(64448.0 / 6561.0), k3[r], in_);
      in_ = fmaf(F(-212.0 / 729.0), k4[r], in_);
      ys[r] = fmaf(dtc, in_, y[r]);
    }
    STAGE(tcur + dtc * F(8.0 / 9.0), k5);

    // k6 @ t + dt
#pragma unroll
    for (int r = 0; r < 4; ++r) {
      float in_ = F(9017.0 / 3168.0) * k1[r];
      in_ = fmaf(F(-355.0 / 33.0), k2[r], in_);
      in_ = fmaf(F(46732.0 / 5247.0), k3[r], in_);
      in_ = fmaf(F(49.0 / 176.0), k4[r], in_);
      in_ = fmaf(F(-5103.0 / 18656.0), k5[r], in_);
      ys[r] = fmaf(dtc, in_, y[r]);
    }
    STAGE(tcur + dtc, k6);

    // y5 (5th-order solution), k7 = f(t+dt, y5)
#pragma unroll
    for (int r = 0; r < 4; ++r) {
      float in_ = F(35.0 / 384.0) * k1[r];
      in_ = fmaf(F(500.0 / 1113.0), k3[r], in_);
      in_ = fmaf(F(125.0 / 192.0), k4[r], in_);
      in_ = fmaf(F(-2187.0 / 6784.0), k5[r], in_);
      in_ = fmaf(F(11.0 / 84.0), k6[r], in_);
      y5[r] = fmaf(dtc, in_, y[r]);
      ys[r] = y5[r];
    }
    STAGE(tcur + dtc, k7);

    // error estimate + deterministic global reduction
    double lsum = 0.0;
#pragma unroll
    for (int r = 0; r < 4; ++r) {
      float ev = F(71.0 / 57600.0) * k1[r];
      ev = fmaf(F(-71.0 / 16695.0), k3[r], ev);
      ev = fmaf(F(71.0 / 1920.0), k4[r], ev);
      ev = fmaf(F(-17253.0 / 339200.0), k5[r], ev);
      ev = fmaf(F(22.0 / 525.0), k6[r], ev);
      ev = fmaf(F(-1.0 / 40.0), k7[r], ev);
      ev *= dtc;
      float sc = 1e-6f + 1e-5f * fmaxf(fabsf(y[r]), fabsf(y5[r]));
      float qq = ev / sc;
      lsum += (double)(qq * qq);
    }
    red[t] = lsum;
    __syncthreads();
    for (int s = 128; s > 0; s >>= 1) {
      if (t < s) red[t] += red[t + s];
      __syncthreads();
    }
    if (t == 0) partials[(step & 1) * NBLK + rg] = red[0];
    grid.sync();
    if (t == 0) {
      double ssum = 0.0;
      const double* pp = partials + (step & 1) * NBLK;
      for (int b = 0; b < NBLK; ++b) ssum += pp[b];  // fixed order: deterministic
      s_bcast = ssum;
    }
    __syncthreads();
    const float err_norm = sqrtf((float)(s_bcast / 131072.0));
    const bool accept = (err_norm <= 1.0f);
    float factor = 0.9f * powf(err_norm + 1e-10f, -0.2f);
    factor = fminf(10.0f, fmaxf(0.2f, factor));
    if (accept) {
      tcur = tcur + dtc;
#pragma unroll
      for (int r = 0; r < 4; ++r) { y[r] = y5[r]; k1[r] = k7[r]; }  // FSAL
    }
    dt = dtc * factor;
  }

  // ---- out = y @ Wl.T + bl ----
  __syncthreads();
  ybuf4[t] = make_float4(y[0], y[1], y[2], y[3]);
  __syncthreads();
  {
    const float* yb = (const float*)ybuf4;  // yb[h*4 + row]
    float acc = bl[lane];
    for (int k = 0; k < 256; ++k)
      acc = fmaf(yb[k * 4 + w], Wlt[k * 64 + lane], acc);
    out[(rg * 4 + w) * 64 + lane] = acc;
  }
}

extern "C" void kernel_launch(void* const* d_in, const int* in_sizes, int n_in,
                              void* d_out, int out_size, void* d_ws, size_t ws_size,
                              hipStream_t stream) {
  const float* x   = (const float*)d_in[0];
  const float* tp  = (const float*)d_in[1];
  const float* Wp  = (const float*)d_in[2];
  const float* bp  = (const float*)d_in[3];
  const float* Wih = (const float*)d_in[4];
  const float* bih = (const float*)d_in[5];
  const float* bhh = (const float*)d_in[7];
  const float* Wl  = (const float*)d_in[8];
  const float* bl  = (const float*)d_in[9];
  float* out = (float*)d_out;
  float* ws_f = (float*)d_ws;
  double* partials = (double*)((char*)d_ws + 983040);
  int nt = in_sizes[1];

  hipLaunchKernelGGL(prep_kernel, dim3(960), dim3(256), 0, stream, Wih, Wp, Wl, ws_f);

  void* args[] = { (void*)&x, (void*)&tp, (void*)&nt, (void*)&bp, (void*)&Wih,
                   (void*)&bih, (void*)&bhh, (void*)&bl, (void*)&ws_f,
                   (void*)&partials, (void*)&out };
  hipLaunchCooperativeKernel((void*)ode_kernel, dim3(NBLK), dim3(256), args, 0, stream);
}